// Round 1
// baseline (145.201 us; speedup 1.0000x reference)
//
#include <hip/hip_runtime.h>
#include <hip/hip_bf16.h>

#define DIMSZ 256
#define HID 4096
#define BATCH 4
#define SEQ 2048
#define NCH 64      // chunks per sequence (carry granularity)
#define CLEN 32     // chunk length
#define SPLITK2 4   // K-splits for fused GEMM2
#define KCHUNK (HID / SPLITK2)   // 1024 channels per block
#define BM2 64      // timesteps per fused-GEMM2 block (= 2 chunks)

typedef __bf16 bf16_t;
typedef __bf16 bf16x8 __attribute__((ext_vector_type(8)));
typedef float  f32x4  __attribute__((ext_vector_type(4)));

__device__ __forceinline__ float sigmoidf_dev(float x) {
    return 1.0f / (1.0f + __expf(-x));
}

// async global->LDS, 16B/lane. LDS dest = wave-uniform base + lane*16.
__device__ __forceinline__ void load_lds16(const bf16_t* g, bf16_t* l) {
    __builtin_amdgcn_global_load_lds(
        (const __attribute__((address_space(1))) void*)g,
        (__attribute__((address_space(3))) void*)l,
        16, 0, 0);
}

__device__ __forceinline__ bf16x8 cvt8(const float* p) {
    bf16x8 o;
    #pragma unroll
    for (int j = 0; j < 8; j++) o[j] = (bf16_t)p[j];
    return o;
}

// ---------------- prep: fused fp32->bf16 convert + MFMA-frag swizzle ----------------
__global__ void prep_kernel(const float* __restrict__ x,
                            const float* __restrict__ WB,
                            const float* __restrict__ WC,
                            bf16_t* __restrict__ xt,
                            bf16_t* __restrict__ WBt,
                            bf16_t* __restrict__ Wt) {
    int i = blockIdx.x * blockDim.x + threadIdx.x;   // 524288
    if (i < 262144) {                                // xt
        int lane = i & 63, m16 = (i >> 6) & 511, ks = i >> 15;
        int row = m16 * 16 + (lane & 15);
        int k   = ks * 32 + (lane >> 4) * 8;
        *(bf16x8*)&xt[(size_t)i * 8] = cvt8(&x[(size_t)row * DIMSZ + k]);
    } else if (i < 393216) {                         // WBt
        int j = i - 262144;
        int lane = j & 63, n16 = (j >> 6) & 255, ks = j >> 14;
        int row = n16 * 16 + (lane & 15);
        int k   = ks * 32 + (lane >> 4) * 8;
        *(bf16x8*)&WBt[(size_t)j * 8] = cvt8(&WB[(size_t)row * DIMSZ + k]);
    } else {                                         // Wt
        int j = i - 393216;
        int lane = j & 63, g = (j >> 6) & 15, ks = j >> 10;
        int row = g * 16 + (lane & 15);
        int k   = ks * 32 + (lane >> 4) * 8;
        *(bf16x8*)&Wt[(size_t)j * 8] = cvt8(&WC[(size_t)row * HID + k]);
    }
}

// ---------------- GEMM1 fused: b = x@WB^T + bB (bf16), + per-chunk totals ----------------
__global__ __launch_bounds__(256)
void gemm1_fused(const bf16_t* __restrict__ xt, const bf16_t* __restrict__ WBt,
                 const float* __restrict__ bias, const float* __restrict__ Adecay,
                 bf16_t* __restrict__ Cg, float* __restrict__ totals)
{
    constexpr int N = HID;
    constexpr int LDTILE = 136;
    __shared__ bf16_t tile[128 * LDTILE];   // 34 KB

    const int tid = threadIdx.x, wave = tid >> 6, lane = tid & 63;
    const int wm = wave >> 1, wn = wave & 1, q = lane >> 4, r16 = lane & 15;
    const int mBase = blockIdx.x * 128, nBase = blockIdx.y * 128;
    const int m16Base = blockIdx.x * 8 + wm * 4;
    const int n16Base = blockIdx.y * 8 + wn * 4;

    f32x4 acc[4][4] = {};

    #pragma unroll 2
    for (int ks = 0; ks < 8; ks++) {
        bf16x8 af[4], bfr[4];
        #pragma unroll
        for (int mt = 0; mt < 4; mt++)
            af[mt] = *(const bf16x8*)&xt[(((size_t)ks * 512 + m16Base + mt) * 64 + lane) * 8];
        #pragma unroll
        for (int nt = 0; nt < 4; nt++)
            bfr[nt] = *(const bf16x8*)&WBt[(((size_t)ks * 256 + n16Base + nt) * 64 + lane) * 8];
        #pragma unroll
        for (int mt = 0; mt < 4; mt++)
            #pragma unroll
            for (int nt = 0; nt < 4; nt++)
                acc[mt][nt] = __builtin_amdgcn_mfma_f32_16x16x32_bf16(
                    af[mt], bfr[nt], acc[mt][nt], 0, 0, 0);
    }

    // acc (+bias) -> LDS tile
    #pragma unroll
    for (int nt = 0; nt < 4; nt++) {
        const int chl = wn * 64 + nt * 16 + r16;
        const float bv = bias[nBase + chl];
        #pragma unroll
        for (int mt = 0; mt < 4; mt++) {
            const int t0 = wm * 64 + mt * 16 + q * 4;
            #pragma unroll
            for (int rg = 0; rg < 4; rg++)
                tile[(t0 + rg) * LDTILE + chl] = (bf16_t)(acc[mt][nt][rg] + bv);
        }
    }
    __syncthreads();

    // coalesced writeback: 8 passes x (16 rows x 128 ch)
    #pragma unroll
    for (int p = 0; p < 8; p++) {
        const int t = p * 16 + (tid >> 4);
        const int ch8 = (tid & 15) << 3;
        *(bf16x8*)&Cg[(size_t)(mBase + t) * N + nBase + ch8] =
            *(const bf16x8*)&tile[t * LDTILE + ch8];
    }

    // chunk totals: 128 channels x 4 chunks, register-batched loads
    #pragma unroll
    for (int t = 0; t < 2; t++) {
        int task = tid + t * 256;
        int ch = task & 127, ck = task >> 7;
        float a = sigmoidf_dev(Adecay[nBase + ch]);
        float v[CLEN];
        #pragma unroll
        for (int i = 0; i < CLEN; i++)
            v[i] = (float)tile[(ck * CLEN + i) * LDTILE + ch];
        float tot = 0.f;
        #pragma unroll
        for (int i = 0; i < CLEN; i++)
            tot = a * tot + v[i];
        int batch = mBase >> 11;
        int cg = ((mBase & 2047) >> 5) + ck;
        totals[(size_t)(batch * NCH + cg) * HID + nBase + ch] = tot;
    }
}

// ---------------- scan over chunk carries, register-batched ----------------
__global__ void scan_carries_kernel(const float* __restrict__ totals,
                                    const float* __restrict__ Adecay,
                                    float* __restrict__ carries)
{
    int gid = blockIdx.x * 64 + threadIdx.x;   // BATCH*HID
    int ch    = gid & (HID - 1);
    int batch = gid >> 12;
    float a = sigmoidf_dev(Adecay[ch]);
    float aC = a;
    #pragma unroll
    for (int i = 0; i < 5; i++) aC *= aC;      // a^32

    float v[NCH];
    #pragma unroll
    for (int c = 0; c < NCH; c++)
        v[c] = totals[(size_t)(batch * NCH + c) * HID + ch];

    float carry = 0.f;
    #pragma unroll
    for (int c = 0; c < NCH; c++) {
        carries[(size_t)(batch * NCH + c) * HID + ch] = carry;
        carry = aC * carry + v[c];
    }
}

// ---------------- fused scan + GEMM2 split-K (BM2=64, bf16 partials) ----------------
// Per block: 64 timesteps (= 2 chunks) x N=256 x 1024-ch K-slice, 4 slabs of 256 ch.
// Both chunks' carries are precomputed -> two independent 32-step scan chains (ILP).
// Halves Wt L2 streaming vs BM2=32 (256 MB total) and doubles MFMA per barrier phase.
// hs (33 KB) doubles as the bf16 epilogue tile after the last slab.
__global__ __launch_bounds__(256)
void gemm2_fused(const bf16_t* __restrict__ bv, const bf16_t* __restrict__ Wt,
                 const float* __restrict__ Adecay, const float* __restrict__ carries,
                 bf16_t* __restrict__ P)
{
    constexpr int CKSTRIDE = BM2 * 32 + 32;    // 2080: +64B stagger between ck slabs
    __shared__ bf16_t hs[16896];               // max(8*2080, 64*264) elements = 33 KB

    const int tid = threadIdx.x, wave = tid >> 6, lane = tid & 63;
    const int q = lane >> 4, r16 = lane & 15;
    const int mBase = blockIdx.x * BM2;
    const int kBase = blockIdx.y * KCHUNK;
    const int batch = mBase >> 11;
    const int chunk0 = (mBase & 2047) >> 5;    // block covers chunk0, chunk0+1

    f32x4 acc[4][4] = {};

    for (int s = 0; s < KCHUNK / 256; s++) {
        const int chSlab = kBase + s * 256;

        if (s > 0) __syncthreads();   // all waves done reading hs before DMA lands

        // stage b-slab -> hs: 32 wave-loads total, 8 per wave
        // (ck = 32-ch group 0..7, g = 16-row group 0..3)
        #pragma unroll
        for (int i = 0; i < 8; i++) {
            int ck = wave * 2 + (i >> 2);
            int g  = i & 3;
            load_lds16(&bv[(size_t)(mBase + g * 16 + (lane >> 2)) * HID
                           + chSlab + ck * 32 + ((lane & 3) << 3)],
                       &hs[ck * CKSTRIDE + g * 512]);
        }

        // seed (coalesced loads, issued during staging)
        const int ck = tid >> 5, ch = tid & 31;
        const int c = chSlab + ck * 32 + ch;
        const float a = sigmoidf_dev(Adecay[c]);
        float st0 = carries[(size_t)(batch * NCH + chunk0) * HID + c];
        float st1 = carries[(size_t)(batch * NCH + chunk0 + 1) * HID + c];

        __syncthreads();   // staging drained

        // in-place scan, register-batched; two independent 32-step chains
        {
            bf16_t* hp = &hs[ck * CKSTRIDE + ch];
            float v[BM2];
            #pragma unroll
            for (int t = 0; t < BM2; t++)
                v[t] = (float)hp[t * 32];
            #pragma unroll
            for (int t = 0; t < CLEN; t++) {
                st0 = a * st0 + v[t];
                v[t] = st0;
                st1 = a * st1 + v[t + CLEN];
                v[t + CLEN] = st1;
            }
            #pragma unroll
            for (int t = 0; t < BM2; t++)
                hp[t * 32] = (bf16_t)v[t];
        }
        __syncthreads();   // hs = h, visible to all waves

        // barrier-free MFMA k-steps; B-frags direct from swizzled global
        const int ksBase = (kBase >> 5) + s * 8;
        #pragma unroll 2
        for (int cki = 0; cki < 8; cki++) {
            bf16x8 af[4], bfr[4];
            #pragma unroll
            for (int nt = 0; nt < 4; nt++)
                bfr[nt] = *(const bf16x8*)&Wt[
                    (((size_t)(ksBase + cki) * 16 + wave * 4 + nt) * 64 + lane) * 8];
            #pragma unroll
            for (int mt = 0; mt < 4; mt++)
                af[mt] = *(const bf16x8*)&hs[cki * CKSTRIDE + (mt * 16 + r16) * 32 + q * 8];
            #pragma unroll
            for (int mt = 0; mt < 4; mt++)
                #pragma unroll
                for (int nt = 0; nt < 4; nt++)
                    acc[mt][nt] = __builtin_amdgcn_mfma_f32_16x16x32_bf16(
                        af[mt], bfr[nt], acc[mt][nt], 0, 0, 0);
        }
    }

    // epilogue: acc -> bf16 LDS tile (reuse hs) -> coalesced 16B partial stores
    __syncthreads();                           // all waves done reading hs
    #pragma unroll
    for (int nt = 0; nt < 4; nt++) {
        const int col = wave * 64 + nt * 16 + r16;
        #pragma unroll
        for (int mt = 0; mt < 4; mt++)
            #pragma unroll
            for (int rg = 0; rg < 4; rg++)
                hs[(mt * 16 + q * 4 + rg) * 264 + col] = (bf16_t)acc[mt][nt][rg];
    }
    __syncthreads();

    bf16_t* Pb = P + (size_t)blockIdx.y * (BATCH * SEQ) * DIMSZ;
    #pragma unroll
    for (int p = 0; p < 8; p++) {
        int task = p * 256 + tid;
        int r = task >> 5, g8 = (task & 31) << 3;
        *(bf16x8*)&Pb[(size_t)(mBase + r) * DIMSZ + g8] =
            *(const bf16x8*)&hs[r * 264 + g8];
    }
}

// ---------------- reduce bf16 partials + bias -> fp32 d_out ----------------
__global__ void reduce_out_kernel(const bf16_t* __restrict__ P,
                                  const float* __restrict__ bias,
                                  float* __restrict__ out, int nTask) {
    int i = blockIdx.x * blockDim.x + threadIdx.x;   // M*256/8
    if (i >= nTask) return;
    int n8 = (i & 31) << 3;
    size_t off = (size_t)i * 8;
    float v[8];
    #pragma unroll
    for (int j = 0; j < 8; j++) v[j] = bias[n8 + j];
    #pragma unroll
    for (int sp = 0; sp < SPLITK2; sp++) {
        bf16x8 p = *(const bf16x8*)&P[(size_t)sp * (BATCH * SEQ) * DIMSZ + off];
        #pragma unroll
        for (int j = 0; j < 8; j++) v[j] += (float)p[j];
    }
    float4* o4 = (float4*)&out[off];
    o4[0] = make_float4(v[0], v[1], v[2], v[3]);
    o4[1] = make_float4(v[4], v[5], v[6], v[7]);
}

extern "C" void kernel_launch(void* const* d_in, const int* in_sizes, int n_in,
                              void* d_out, int out_size, void* d_ws, size_t ws_size,
                              hipStream_t stream)
{
    const float* x  = (const float*)d_in[0];
    const float* WB = (const float*)d_in[1];
    const float* bB = (const float*)d_in[2];
    const float* WC = (const float*)d_in[3];
    const float* bC = (const float*)d_in[4];
    const float* A  = (const float*)d_in[5];

    char* ws = (char*)d_ws;
    size_t off = 0;
    bf16_t* xt   = (bf16_t*)(ws + off); off += (size_t)BATCH * SEQ * DIMSZ * 2;  // 4 MB
    bf16_t* WBt  = (bf16_t*)(ws + off); off += (size_t)HID * DIMSZ * 2;          // 2 MB
    bf16_t* Wt   = (bf16_t*)(ws + off); off += (size_t)DIMSZ * HID * 2;          // 2 MB
    bf16_t* bbuf = (bf16_t*)(ws + off); off += (size_t)BATCH * SEQ * HID * 2;    // 64 MB
    bf16_t* partials = (bf16_t*)(ws + off); off += (size_t)SPLITK2 * BATCH * SEQ * DIMSZ * 2; // 16.75 MB
    float* totals   = (float*)(ws + off); off += (size_t)BATCH * NCH * HID * 4;
    float* carries  = (float*)(ws + off); off += (size_t)BATCH * NCH * HID * 4;

    const int M = BATCH * SEQ;   // 8192

    prep_kernel<<<2048, 256, 0, stream>>>(x, WB, WC, xt, WBt, Wt);

    dim3 g1(M / 128, HID / 128);
    gemm1_fused<<<g1, 256, 0, stream>>>(xt, WBt, bB, A, bbuf, totals);

    scan_carries_kernel<<<256, 64, 0, stream>>>(totals, A, carries);

    dim3 g2(M / BM2, SPLITK2);
    gemm2_fused<<<g2, 256, 0, stream>>>(bbuf, Wt, A, carries, partials);

    int nTask = M * DIMSZ / 8;
    reduce_out_kernel<<<(nTask + 255) / 256, 256, 0, stream>>>(
        partials, bC, (float*)d_out, nTask);
}

// Round 2
// 144.875 us; speedup vs baseline: 1.0023x; 1.0023x over previous
//
#include <hip/hip_runtime.h>
#include <hip/hip_bf16.h>

#define DIMSZ 256
#define HID 4096
#define BATCH 4
#define SEQ 2048
#define NCH 64      // chunks per sequence (carry granularity)
#define CLEN 32     // chunk length
#define SPLITK2 4   // K-splits for fused GEMM2
#define KCHUNK (HID / SPLITK2)   // 1024 channels per block
#define BM2 64      // timesteps per fused-GEMM2 block (= 2 chunks)

typedef __bf16 bf16_t;
typedef __bf16 bf16x8 __attribute__((ext_vector_type(8)));
typedef float  f32x4  __attribute__((ext_vector_type(4)));

__device__ __forceinline__ float sigmoidf_dev(float x) {
    return 1.0f / (1.0f + __expf(-x));
}

// async global->LDS, 16B/lane. LDS dest = wave-uniform base + lane*16.
__device__ __forceinline__ void load_lds16(const bf16_t* g, bf16_t* l) {
    __builtin_amdgcn_global_load_lds(
        (const __attribute__((address_space(1))) void*)g,
        (__attribute__((address_space(3))) void*)l,
        16, 0, 0);
}

__device__ __forceinline__ bf16x8 cvt8(const float* p) {
    bf16x8 o;
    #pragma unroll
    for (int j = 0; j < 8; j++) o[j] = (bf16_t)p[j];
    return o;
}

// ---------------- prep: fused fp32->bf16 convert + MFMA-frag swizzle ----------------
__global__ void prep_kernel(const float* __restrict__ x,
                            const float* __restrict__ WB,
                            const float* __restrict__ WC,
                            bf16_t* __restrict__ xt,
                            bf16_t* __restrict__ WBt,
                            bf16_t* __restrict__ Wt) {
    int i = blockIdx.x * blockDim.x + threadIdx.x;   // 524288
    if (i < 262144) {                                // xt
        int lane = i & 63, m16 = (i >> 6) & 511, ks = i >> 15;
        int row = m16 * 16 + (lane & 15);
        int k   = ks * 32 + (lane >> 4) * 8;
        *(bf16x8*)&xt[(size_t)i * 8] = cvt8(&x[(size_t)row * DIMSZ + k]);
    } else if (i < 393216) {                         // WBt
        int j = i - 262144;
        int lane = j & 63, n16 = (j >> 6) & 255, ks = j >> 14;
        int row = n16 * 16 + (lane & 15);
        int k   = ks * 32 + (lane >> 4) * 8;
        *(bf16x8*)&WBt[(size_t)j * 8] = cvt8(&WB[(size_t)row * DIMSZ + k]);
    } else {                                         // Wt
        int j = i - 393216;
        int lane = j & 63, g = (j >> 6) & 15, ks = j >> 10;
        int row = g * 16 + (lane & 15);
        int k   = ks * 32 + (lane >> 4) * 8;
        *(bf16x8*)&Wt[(size_t)j * 8] = cvt8(&WC[(size_t)row * HID + k]);
    }
}

// ---------------- GEMM1 fused: b = x@WB^T + bB (bf16), + per-chunk totals ----------------
__global__ __launch_bounds__(256)
void gemm1_fused(const bf16_t* __restrict__ xt, const bf16_t* __restrict__ WBt,
                 const float* __restrict__ bias, const float* __restrict__ Adecay,
                 bf16_t* __restrict__ Cg, float* __restrict__ totals)
{
    constexpr int N = HID;
    constexpr int LDTILE = 136;
    __shared__ bf16_t tile[128 * LDTILE];   // 34 KB

    const int tid = threadIdx.x, wave = tid >> 6, lane = tid & 63;
    const int wm = wave >> 1, wn = wave & 1, q = lane >> 4, r16 = lane & 15;
    const int mBase = blockIdx.x * 128, nBase = blockIdx.y * 128;
    const int m16Base = blockIdx.x * 8 + wm * 4;
    const int n16Base = blockIdx.y * 8 + wn * 4;

    f32x4 acc[4][4] = {};

    #pragma unroll 2
    for (int ks = 0; ks < 8; ks++) {
        bf16x8 af[4], bfr[4];
        #pragma unroll
        for (int mt = 0; mt < 4; mt++)
            af[mt] = *(const bf16x8*)&xt[(((size_t)ks * 512 + m16Base + mt) * 64 + lane) * 8];
        #pragma unroll
        for (int nt = 0; nt < 4; nt++)
            bfr[nt] = *(const bf16x8*)&WBt[(((size_t)ks * 256 + n16Base + nt) * 64 + lane) * 8];
        #pragma unroll
        for (int mt = 0; mt < 4; mt++)
            #pragma unroll
            for (int nt = 0; nt < 4; nt++)
                acc[mt][nt] = __builtin_amdgcn_mfma_f32_16x16x32_bf16(
                    af[mt], bfr[nt], acc[mt][nt], 0, 0, 0);
    }

    // acc (+bias) -> LDS tile
    #pragma unroll
    for (int nt = 0; nt < 4; nt++) {
        const int chl = wn * 64 + nt * 16 + r16;
        const float bv = bias[nBase + chl];
        #pragma unroll
        for (int mt = 0; mt < 4; mt++) {
            const int t0 = wm * 64 + mt * 16 + q * 4;
            #pragma unroll
            for (int rg = 0; rg < 4; rg++)
                tile[(t0 + rg) * LDTILE + chl] = (bf16_t)(acc[mt][nt][rg] + bv);
        }
    }
    __syncthreads();

    // coalesced writeback: 8 passes x (16 rows x 128 ch)
    #pragma unroll
    for (int p = 0; p < 8; p++) {
        const int t = p * 16 + (tid >> 4);
        const int ch8 = (tid & 15) << 3;
        *(bf16x8*)&Cg[(size_t)(mBase + t) * N + nBase + ch8] =
            *(const bf16x8*)&tile[t * LDTILE + ch8];
    }

    // chunk totals: 128 channels x 4 chunks, register-batched loads
    #pragma unroll
    for (int t = 0; t < 2; t++) {
        int task = tid + t * 256;
        int ch = task & 127, ck = task >> 7;
        float a = sigmoidf_dev(Adecay[nBase + ch]);
        float v[CLEN];
        #pragma unroll
        for (int i = 0; i < CLEN; i++)
            v[i] = (float)tile[(ck * CLEN + i) * LDTILE + ch];
        float tot = 0.f;
        #pragma unroll
        for (int i = 0; i < CLEN; i++)
            tot = a * tot + v[i];
        int batch = mBase >> 11;
        int cg = ((mBase & 2047) >> 5) + ck;
        totals[(size_t)(batch * NCH + cg) * HID + nBase + ch] = tot;
    }
}

// ---------------- scan over chunk carries, register-batched ----------------
__global__ void scan_carries_kernel(const float* __restrict__ totals,
                                    const float* __restrict__ Adecay,
                                    float* __restrict__ carries)
{
    int gid = blockIdx.x * 64 + threadIdx.x;   // BATCH*HID
    int ch    = gid & (HID - 1);
    int batch = gid >> 12;
    float a = sigmoidf_dev(Adecay[ch]);
    float aC = a;
    #pragma unroll
    for (int i = 0; i < 5; i++) aC *= aC;      // a^32

    float v[NCH];
    #pragma unroll
    for (int c = 0; c < NCH; c++)
        v[c] = totals[(size_t)(batch * NCH + c) * HID + ch];

    float carry = 0.f;
    #pragma unroll
    for (int c = 0; c < NCH; c++) {
        carries[(size_t)(batch * NCH + c) * HID + ch] = carry;
        carry = aC * carry + v[c];
    }
}

// ---------------- fused scan + GEMM2 split-K (BM2=64, bf16 partials) ----------------
// Per block: 64 timesteps (= 2 chunks) x N=256 x 1024-ch K-slice, 4 slabs of 256 ch.
// Scan is done in TWO sequential 32-register halves (one per chunk) to keep peak
// VGPR < 256: v[64] + acc[4][4] was at the occupancy cliff (1 wave/SIMD), which
// serialized the scan phases against nothing. __launch_bounds__(256,2) pins
// 2 blocks/CU so one block's scan/barrier drains hide under the other's MFMAs.
// hs (33 KB) doubles as the bf16 epilogue tile after the last slab.
__global__ __launch_bounds__(256, 2)
void gemm2_fused(const bf16_t* __restrict__ bv, const bf16_t* __restrict__ Wt,
                 const float* __restrict__ Adecay, const float* __restrict__ carries,
                 bf16_t* __restrict__ P)
{
    constexpr int CKSTRIDE = BM2 * 32 + 32;    // 2080: +64B stagger between ck slabs
    __shared__ bf16_t hs[16896];               // max(8*2080, 64*264) elements = 33 KB

    const int tid = threadIdx.x, wave = tid >> 6, lane = tid & 63;
    const int q = lane >> 4, r16 = lane & 15;
    const int mBase = blockIdx.x * BM2;
    const int kBase = blockIdx.y * KCHUNK;
    const int batch = mBase >> 11;
    const int chunk0 = (mBase & 2047) >> 5;    // block covers chunk0, chunk0+1

    f32x4 acc[4][4] = {};

    for (int s = 0; s < KCHUNK / 256; s++) {
        const int chSlab = kBase + s * 256;

        if (s > 0) __syncthreads();   // all waves done reading hs before DMA lands

        // stage b-slab -> hs: 32 wave-loads total, 8 per wave
        // (ck = 32-ch group 0..7, g = 16-row group 0..3)
        #pragma unroll
        for (int i = 0; i < 8; i++) {
            int ck = wave * 2 + (i >> 2);
            int g  = i & 3;
            load_lds16(&bv[(size_t)(mBase + g * 16 + (lane >> 2)) * HID
                           + chSlab + ck * 32 + ((lane & 3) << 3)],
                       &hs[ck * CKSTRIDE + g * 512]);
        }

        // seed (coalesced loads, issued during staging)
        const int ck = tid >> 5, ch = tid & 31;
        const int c = chSlab + ck * 32 + ch;
        const float a = sigmoidf_dev(Adecay[c]);
        float st0 = carries[(size_t)(batch * NCH + chunk0) * HID + c];
        float st1 = carries[(size_t)(batch * NCH + chunk0 + 1) * HID + c];

        __syncthreads();   // staging drained

        // in-place scan, register-batched; two sequential 32-reg halves
        // (keeps peak VGPR well under the 256 occupancy cliff)
        {
            bf16_t* hp = &hs[ck * CKSTRIDE + ch];
            float v[CLEN];
            #pragma unroll
            for (int t = 0; t < CLEN; t++)
                v[t] = (float)hp[t * 32];
            #pragma unroll
            for (int t = 0; t < CLEN; t++) {
                st0 = a * st0 + v[t];
                v[t] = st0;
            }
            #pragma unroll
            for (int t = 0; t < CLEN; t++)
                hp[t * 32] = (bf16_t)v[t];

            __builtin_amdgcn_sched_barrier(0);   // keep halves' live ranges apart

            #pragma unroll
            for (int t = 0; t < CLEN; t++)
                v[t] = (float)hp[(t + CLEN) * 32];
            #pragma unroll
            for (int t = 0; t < CLEN; t++) {
                st1 = a * st1 + v[t];
                v[t] = st1;
            }
            #pragma unroll
            for (int t = 0; t < CLEN; t++)
                hp[(t + CLEN) * 32] = (bf16_t)v[t];
        }
        __syncthreads();   // hs = h, visible to all waves

        // barrier-free MFMA k-steps; B-frags direct from swizzled global
        const int ksBase = (kBase >> 5) + s * 8;
        #pragma unroll 2
        for (int cki = 0; cki < 8; cki++) {
            bf16x8 af[4], bfr[4];
            #pragma unroll
            for (int nt = 0; nt < 4; nt++)
                bfr[nt] = *(const bf16x8*)&Wt[
                    (((size_t)(ksBase + cki) * 16 + wave * 4 + nt) * 64 + lane) * 8];
            #pragma unroll
            for (int mt = 0; mt < 4; mt++)
                af[mt] = *(const bf16x8*)&hs[cki * CKSTRIDE + (mt * 16 + r16) * 32 + q * 8];
            #pragma unroll
            for (int mt = 0; mt < 4; mt++)
                #pragma unroll
                for (int nt = 0; nt < 4; nt++)
                    acc[mt][nt] = __builtin_amdgcn_mfma_f32_16x16x32_bf16(
                        af[mt], bfr[nt], acc[mt][nt], 0, 0, 0);
        }
    }

    // epilogue: acc -> bf16 LDS tile (reuse hs) -> coalesced 16B partial stores
    __syncthreads();                           // all waves done reading hs
    #pragma unroll
    for (int nt = 0; nt < 4; nt++) {
        const int col = wave * 64 + nt * 16 + r16;
        #pragma unroll
        for (int mt = 0; mt < 4; mt++)
            #pragma unroll
            for (int rg = 0; rg < 4; rg++)
                hs[(mt * 16 + q * 4 + rg) * 264 + col] = (bf16_t)acc[mt][nt][rg];
    }
    __syncthreads();

    bf16_t* Pb = P + (size_t)blockIdx.y * (BATCH * SEQ) * DIMSZ;
    #pragma unroll
    for (int p = 0; p < 8; p++) {
        int task = p * 256 + tid;
        int r = task >> 5, g8 = (task & 31) << 3;
        *(bf16x8*)&Pb[(size_t)(mBase + r) * DIMSZ + g8] =
            *(const bf16x8*)&hs[r * 264 + g8];
    }
}

// ---------------- reduce bf16 partials + bias -> fp32 d_out ----------------
__global__ void reduce_out_kernel(const bf16_t* __restrict__ P,
                                  const float* __restrict__ bias,
                                  float* __restrict__ out, int nTask) {
    int i = blockIdx.x * blockDim.x + threadIdx.x;   // M*256/8
    if (i >= nTask) return;
    int n8 = (i & 31) << 3;
    size_t off = (size_t)i * 8;
    float v[8];
    #pragma unroll
    for (int j = 0; j < 8; j++) v[j] = bias[n8 + j];
    #pragma unroll
    for (int sp = 0; sp < SPLITK2; sp++) {
        bf16x8 p = *(const bf16x8*)&P[(size_t)sp * (BATCH * SEQ) * DIMSZ + off];
        #pragma unroll
        for (int j = 0; j < 8; j++) v[j] += (float)p[j];
    }
    float4* o4 = (float4*)&out[off];
    o4[0] = make_float4(v[0], v[1], v[2], v[3]);
    o4[1] = make_float4(v[4], v[5], v[6], v[7]);
}

extern "C" void kernel_launch(void* const* d_in, const int* in_sizes, int n_in,
                              void* d_out, int out_size, void* d_ws, size_t ws_size,
                              hipStream_t stream)
{
    const float* x  = (const float*)d_in[0];
    const float* WB = (const float*)d_in[1];
    const float* bB = (const float*)d_in[2];
    const float* WC = (const float*)d_in[3];
    const float* bC = (const float*)d_in[4];
    const float* A  = (const float*)d_in[5];

    char* ws = (char*)d_ws;
    size_t off = 0;
    bf16_t* xt   = (bf16_t*)(ws + off); off += (size_t)BATCH * SEQ * DIMSZ * 2;  // 4 MB
    bf16_t* WBt  = (bf16_t*)(ws + off); off += (size_t)HID * DIMSZ * 2;          // 2 MB
    bf16_t* Wt   = (bf16_t*)(ws + off); off += (size_t)DIMSZ * HID * 2;          // 2 MB
    bf16_t* bbuf = (bf16_t*)(ws + off); off += (size_t)BATCH * SEQ * HID * 2;    // 64 MB
    bf16_t* partials = (bf16_t*)(ws + off); off += (size_t)SPLITK2 * BATCH * SEQ * DIMSZ * 2; // 16.75 MB
    float* totals   = (float*)(ws + off); off += (size_t)BATCH * NCH * HID * 4;
    float* carries  = (float*)(ws + off); off += (size_t)BATCH * NCH * HID * 4;

    const int M = BATCH * SEQ;   // 8192

    prep_kernel<<<2048, 256, 0, stream>>>(x, WB, WC, xt, WBt, Wt);

    dim3 g1(M / 128, HID / 128);
    gemm1_fused<<<g1, 256, 0, stream>>>(xt, WBt, bB, A, bbuf, totals);

    scan_carries_kernel<<<256, 64, 0, stream>>>(totals, A, carries);

    dim3 g2(M / BM2, SPLITK2);
    gemm2_fused<<<g2, 256, 0, stream>>>(bbuf, Wt, A, carries, partials);

    int nTask = M * DIMSZ / 8;
    reduce_out_kernel<<<(nTask + 255) / 256, 256, 0, stream>>>(
        partials, bC, (float*)d_out, nTask);
}

// Round 4
// 141.415 us; speedup vs baseline: 1.0268x; 1.0245x over previous
//
#include <hip/hip_runtime.h>
#include <hip/hip_bf16.h>

#define DIMSZ 256
#define HID 4096
#define BATCH 4
#define SEQ 2048
#define NCH 64      // chunks per sequence (carry granularity)
#define CLEN 32     // chunk length
#define SPLITK2 4   // K-splits for fused GEMM2
#define KCHUNK (HID / SPLITK2)   // 1024 channels per block
#define BM2 64      // timesteps per fused-GEMM2 block (= 2 chunks)

typedef __bf16 bf16_t;
typedef __bf16 bf16x4 __attribute__((ext_vector_type(4)));
typedef __bf16 bf16x8 __attribute__((ext_vector_type(8)));
typedef float  f32x4  __attribute__((ext_vector_type(4)));

__device__ __forceinline__ float sigmoidf_dev(float x) {
    return 1.0f / (1.0f + __expf(-x));
}

// async global->LDS, 16B/lane. LDS dest = wave-uniform base + lane*16.
__device__ __forceinline__ void load_lds16(const bf16_t* g, bf16_t* l) {
    __builtin_amdgcn_global_load_lds(
        (const __attribute__((address_space(1))) void*)g,
        (__attribute__((address_space(3))) void*)l,
        16, 0, 0);
}

__device__ __forceinline__ bf16x8 cvt8(const float* p) {
    bf16x8 o;
    #pragma unroll
    for (int j = 0; j < 8; j++) o[j] = (bf16_t)p[j];
    return o;
}

// ---------------- prep: fused fp32->bf16 convert + MFMA-frag swizzle ----------------
__global__ void prep_kernel(const float* __restrict__ x,
                            const float* __restrict__ WB,
                            const float* __restrict__ WC,
                            bf16_t* __restrict__ xt,
                            bf16_t* __restrict__ WBt,
                            bf16_t* __restrict__ Wt) {
    int i = blockIdx.x * blockDim.x + threadIdx.x;   // 524288
    if (i < 262144) {                                // xt
        int lane = i & 63, m16 = (i >> 6) & 511, ks = i >> 15;
        int row = m16 * 16 + (lane & 15);
        int k   = ks * 32 + (lane >> 4) * 8;
        *(bf16x8*)&xt[(size_t)i * 8] = cvt8(&x[(size_t)row * DIMSZ + k]);
    } else if (i < 393216) {                         // WBt
        int j = i - 262144;
        int lane = j & 63, n16 = (j >> 6) & 255, ks = j >> 14;
        int row = n16 * 16 + (lane & 15);
        int k   = ks * 32 + (lane >> 4) * 8;
        *(bf16x8*)&WBt[(size_t)j * 8] = cvt8(&WB[(size_t)row * DIMSZ + k]);
    } else {                                         // Wt
        int j = i - 393216;
        int lane = j & 63, g = (j >> 6) & 15, ks = j >> 10;
        int row = g * 16 + (lane & 15);
        int k   = ks * 32 + (lane >> 4) * 8;
        *(bf16x8*)&Wt[(size_t)j * 8] = cvt8(&WC[(size_t)row * HID + k]);
    }
}

// ---------------- GEMM1 fused: b = x@WB^T + bB (bf16, ch-major out), + chunk totals ----
// tile is [ch][t] (LDT=136): acc->tile = b64 writes (4 consecutive t),
// totals = b128 reads along t, writeback = b128 rows into ch-major bbuf.
__global__ __launch_bounds__(256)
void gemm1_fused(const bf16_t* __restrict__ xt, const bf16_t* __restrict__ WBt,
                 const float* __restrict__ bias, const float* __restrict__ Adecay,
                 bf16_t* __restrict__ Cg, float* __restrict__ totals)
{
    constexpr int LDT = 136;                // elems; 272 B row stride (16B-aligned)
    __shared__ bf16_t tile[128 * LDT];      // 34.8 KB, [ch][t]

    const int tid = threadIdx.x, wave = tid >> 6, lane = tid & 63;
    const int wm = wave >> 1, wn = wave & 1, q = lane >> 4, r16 = lane & 15;
    const int mBase = blockIdx.x * 128, nBase = blockIdx.y * 128;
    const int m16Base = blockIdx.x * 8 + wm * 4;
    const int n16Base = blockIdx.y * 8 + wn * 4;
    const int batch = mBase >> 11, tIn = mBase & 2047;

    f32x4 acc[4][4] = {};

    #pragma unroll 2
    for (int ks = 0; ks < 8; ks++) {
        bf16x8 af[4], bfr[4];
        #pragma unroll
        for (int mt = 0; mt < 4; mt++)
            af[mt] = *(const bf16x8*)&xt[(((size_t)ks * 512 + m16Base + mt) * 64 + lane) * 8];
        #pragma unroll
        for (int nt = 0; nt < 4; nt++)
            bfr[nt] = *(const bf16x8*)&WBt[(((size_t)ks * 256 + n16Base + nt) * 64 + lane) * 8];
        #pragma unroll
        for (int mt = 0; mt < 4; mt++)
            #pragma unroll
            for (int nt = 0; nt < 4; nt++)
                acc[mt][nt] = __builtin_amdgcn_mfma_f32_16x16x32_bf16(
                    af[mt], bfr[nt], acc[mt][nt], 0, 0, 0);
    }

    // acc (+bias) -> [ch][t] tile, packed b64 (4 consecutive t per acc quad)
    #pragma unroll
    for (int nt = 0; nt < 4; nt++) {
        const int chl = wn * 64 + nt * 16 + r16;
        const float bv = bias[nBase + chl];
        #pragma unroll
        for (int mt = 0; mt < 4; mt++) {
            const int t0 = wm * 64 + mt * 16 + q * 4;
            bf16x4 pk;
            #pragma unroll
            for (int rg = 0; rg < 4; rg++)
                pk[rg] = (bf16_t)(acc[mt][nt][rg] + bv);
            *(bf16x4*)&tile[chl * LDT + t0] = pk;
        }
    }
    __syncthreads();

    // writeback: ch-major bbuf, 256-B contiguous runs (16 lanes/ch-row)
    #pragma unroll
    for (int p = 0; p < 8; p++) {
        const int task = p * 256 + tid;
        const int ch = task >> 4, o = task & 15;
        *(bf16x8*)&Cg[((size_t)batch * HID + nBase + ch) * SEQ + tIn + o * 8] =
            *(const bf16x8*)&tile[ch * LDT + o * 8];
    }

    // chunk totals: vectorized b128 reads along t
    #pragma unroll
    for (int t = 0; t < 2; t++) {
        const int task = tid + t * 256;
        const int ch = task & 127, ck = task >> 7;
        const float a = sigmoidf_dev(Adecay[nBase + ch]);
        float tot = 0.f;
        #pragma unroll
        for (int o = 0; o < 4; o++) {
            bf16x8 v8 = *(const bf16x8*)&tile[ch * LDT + ck * CLEN + o * 8];
            #pragma unroll
            for (int j = 0; j < 8; j++)
                tot = a * tot + (float)v8[j];
        }
        const int cg = (tIn >> 5) + ck;
        totals[(size_t)(batch * NCH + cg) * HID + nBase + ch] = tot;
    }
}

// ---------------- scan over chunk carries, register-batched ----------------
__global__ void scan_carries_kernel(const float* __restrict__ totals,
                                    const float* __restrict__ Adecay,
                                    float* __restrict__ carries)
{
    int gid = blockIdx.x * 64 + threadIdx.x;   // BATCH*HID
    int ch    = gid & (HID - 1);
    int batch = gid >> 12;
    float a = sigmoidf_dev(Adecay[ch]);
    float aC = a;
    #pragma unroll
    for (int i = 0; i < 5; i++) aC *= aC;      // a^32

    float v[NCH];
    #pragma unroll
    for (int c = 0; c < NCH; c++)
        v[c] = totals[(size_t)(batch * NCH + c) * HID + ch];

    float carry = 0.f;
    #pragma unroll
    for (int c = 0; c < NCH; c++) {
        carries[(size_t)(batch * NCH + c) * HID + ch] = carry;
        carry = aC * carry + v[c];
    }
}

// ---------------- fused scan + GEMM2 split-K (ch-major staging) ----------------
// hs2 [ch(tid)][64t] = scan staging (DMA'd ch-major from ch-major bbuf, with
// per-lane oct rotation baked into the DMA source so scan's b128 reads are
// bank-rotated). Scan: 8x b128 reads + interleaved st0/st1 chains + u16 writes
// into the unchanged MFMA [t][ch] region hs. Separate in/out regions let slab
// s+1's DMA overlap slab s's MFMAs. Seeds prefetched for all 4 slabs.
__global__ __launch_bounds__(256, 2)
void gemm2_fused(const bf16_t* __restrict__ bv, const bf16_t* __restrict__ Wt,
                 const float* __restrict__ Adecay, const float* __restrict__ carries,
                 bf16_t* __restrict__ P)
{
    constexpr int CKSTRIDE = BM2 * 32 + 32;    // 2080
    __shared__ bf16_t hs[16896];               // MFMA [t][ch] tile / epilogue, 33.8 KB
    __shared__ bf16_t hs2[16384];              // scan staging [ch][64], 32 KB

    const int tid = threadIdx.x, wave = tid >> 6, lane = tid & 63;
    const int q = lane >> 4, r16 = lane & 15;
    const int mBase = blockIdx.x * BM2;
    const int kBase = blockIdx.y * KCHUNK;
    const int batch = mBase >> 11, tIn = mBase & 2047;
    const int chunk0 = tIn >> 5;               // block covers chunk0, chunk0+1

    // DMA source-oct rotation: LDS slot (lane&7) of column (lane>>3 mod 8)
    // holds global oct ((lane&7)-(lane>>3))&7; scan reads slot (k+ch)&7 -> oct k.
    const int srcOct = ((lane & 7) - (lane >> 3)) & 7;

    // prefetch per-slab scan constants (static indexing; s-loop fully unrolled)
    float aD[4], sd0[4], sd1[4];
    #pragma unroll
    for (int s = 0; s < 4; s++) {
        const int c = kBase + s * 256 + tid;
        aD[s]  = Adecay[c];
        sd0[s] = carries[(size_t)(batch * NCH + chunk0) * HID + c];
        sd1[s] = carries[(size_t)(batch * NCH + chunk0 + 1) * HID + c];
    }

    f32x4 acc[4][4] = {};

    // prologue: stage slab 0 -> hs2
    {
        const size_t rowBase = (size_t)batch * HID + kBase;
        #pragma unroll
        for (int i = 0; i < 8; i++) {
            const int g = wave * 8 + i;
            load_lds16(&bv[(rowBase + g * 8 + (lane >> 3)) * SEQ + tIn + srcOct * 8],
                       &hs2[g * 512]);
        }
    }

    #pragma unroll
    for (int s = 0; s < 4; s++) {
        __syncthreads();   // DMA drained (barrier waits vmcnt); hs free of MFMA readers

        // ---- scan slab s: hs2 -> hs (st0/st1 chains interleaved for ILP) ----
        {
            const float a = sigmoidf_dev(aD[s]);
            float st0 = sd0[s], st1 = sd1[s];
            const int rot = tid & 7;
            bf16_t* hw = &hs[(tid >> 5) * CKSTRIDE + (tid & 31)];
            const bf16_t* hr = &hs2[tid * 64];
            #pragma unroll
            for (int k = 0; k < 4; k++) {
                bf16x8 va = *(const bf16x8*)&hr[(((k + rot) & 7)) << 3];
                bf16x8 vb = *(const bf16x8*)&hr[(((k + 4 + rot) & 7)) << 3];
                #pragma unroll
                for (int j = 0; j < 8; j++) {
                    st0 = a * st0 + (float)va[j];
                    st1 = a * st1 + (float)vb[j];
                    hw[(k * 8 + j) * 32]        = (bf16_t)st0;
                    hw[((k + 4) * 8 + j) * 32]  = (bf16_t)st1;
                }
            }
        }
        __syncthreads();   // hs ready for MFMA; hs2 fully consumed

        // ---- stage slab s+1 (overlaps the MFMA phase below) ----
        if (s < 3) {
            const size_t rowBase = (size_t)batch * HID + kBase + (s + 1) * 256;
            #pragma unroll
            for (int i = 0; i < 8; i++) {
                const int g = wave * 8 + i;
                load_lds16(&bv[(rowBase + g * 8 + (lane >> 3)) * SEQ + tIn + srcOct * 8],
                           &hs2[g * 512]);
            }
        }

        // ---- barrier-free MFMA k-steps; B-frags direct from swizzled global ----
        const int ksBase = (kBase >> 5) + s * 8;
        #pragma unroll 2
        for (int cki = 0; cki < 8; cki++) {
            bf16x8 af[4], bfr[4];
            #pragma unroll
            for (int nt = 0; nt < 4; nt++)
                bfr[nt] = *(const bf16x8*)&Wt[
                    (((size_t)(ksBase + cki) * 16 + wave * 4 + nt) * 64 + lane) * 8];
            #pragma unroll
            for (int mt = 0; mt < 4; mt++)
                af[mt] = *(const bf16x8*)&hs[cki * CKSTRIDE + (mt * 16 + r16) * 32 + q * 8];
            #pragma unroll
            for (int mt = 0; mt < 4; mt++)
                #pragma unroll
                for (int nt = 0; nt < 4; nt++)
                    acc[mt][nt] = __builtin_amdgcn_mfma_f32_16x16x32_bf16(
                        af[mt], bfr[nt], acc[mt][nt], 0, 0, 0);
        }
    }

    // epilogue: acc -> bf16 LDS tile (reuse hs) -> coalesced 16B partial stores
    __syncthreads();                           // all waves done reading hs
    #pragma unroll
    for (int nt = 0; nt < 4; nt++) {
        const int col = wave * 64 + nt * 16 + r16;
        #pragma unroll
        for (int mt = 0; mt < 4; mt++)
            #pragma unroll
            for (int rg = 0; rg < 4; rg++)
                hs[(mt * 16 + q * 4 + rg) * 264 + col] = (bf16_t)acc[mt][nt][rg];
    }
    __syncthreads();

    bf16_t* Pb = P + (size_t)blockIdx.y * (BATCH * SEQ) * DIMSZ;
    #pragma unroll
    for (int p = 0; p < 8; p++) {
        int task = p * 256 + tid;
        int r = task >> 5, g8 = (task & 31) << 3;
        *(bf16x8*)&Pb[(size_t)(mBase + r) * DIMSZ + g8] =
            *(const bf16x8*)&hs[r * 264 + g8];
    }
}

// ---------------- reduce bf16 partials + bias -> fp32 d_out ----------------
__global__ void reduce_out_kernel(const bf16_t* __restrict__ P,
                                  const float* __restrict__ bias,
                                  float* __restrict__ out, int nTask) {
    int i = blockIdx.x * blockDim.x + threadIdx.x;   // M*256/8
    if (i >= nTask) return;
    int n8 = (i & 31) << 3;
    size_t off = (size_t)i * 8;
    float v[8];
    #pragma unroll
    for (int j = 0; j < 8; j++) v[j] = bias[n8 + j];
    #pragma unroll
    for (int sp = 0; sp < SPLITK2; sp++) {
        bf16x8 p = *(const bf16x8*)&P[(size_t)sp * (BATCH * SEQ) * DIMSZ + off];
        #pragma unroll
        for (int j = 0; j < 8; j++) v[j] += (float)p[j];
    }
    float4* o4 = (float4*)&out[off];
    o4[0] = make_float4(v[0], v[1], v[2], v[3]);
    o4[1] = make_float4(v[4], v[5], v[6], v[7]);
}

extern "C" void kernel_launch(void* const* d_in, const int* in_sizes, int n_in,
                              void* d_out, int out_size, void* d_ws, size_t ws_size,
                              hipStream_t stream)
{
    const float* x  = (const float*)d_in[0];
    const float* WB = (const float*)d_in[1];
    const float* bB = (const float*)d_in[2];
    const float* WC = (const float*)d_in[3];
    const float* bC = (const float*)d_in[4];
    const float* A  = (const float*)d_in[5];

    char* ws = (char*)d_ws;
    size_t off = 0;
    bf16_t* xt   = (bf16_t*)(ws + off); off += (size_t)BATCH * SEQ * DIMSZ * 2;  // 4 MB
    bf16_t* WBt  = (bf16_t*)(ws + off); off += (size_t)HID * DIMSZ * 2;          // 2 MB
    bf16_t* Wt   = (bf16_t*)(ws + off); off += (size_t)DIMSZ * HID * 2;          // 2 MB
    bf16_t* bbuf = (bf16_t*)(ws + off); off += (size_t)BATCH * SEQ * HID * 2;    // 64 MB, ch-major
    bf16_t* partials = (bf16_t*)(ws + off); off += (size_t)SPLITK2 * BATCH * SEQ * DIMSZ * 2; // 16.75 MB
    float* totals   = (float*)(ws + off); off += (size_t)BATCH * NCH * HID * 4;
    float* carries  = (float*)(ws + off); off += (size_t)BATCH * NCH * HID * 4;

    const int M = BATCH * SEQ;   // 8192

    prep_kernel<<<2048, 256, 0, stream>>>(x, WB, WC, xt, WBt, Wt);

    dim3 g1(M / 128, HID / 128);
    gemm1_fused<<<g1, 256, 0, stream>>>(xt, WBt, bB, A, bbuf, totals);

    scan_carries_kernel<<<256, 64, 0, stream>>>(totals, A, carries);

    dim3 g2(M / BM2, SPLITK2);
    gemm2_fused<<<g2, 256, 0, stream>>>(bbuf, Wt, A, carries, partials);

    int nTask = M * DIMSZ / 8;
    reduce_out_kernel<<<(nTask + 255) / 256, 256, 0, stream>>>(
        partials, bC, (float*)d_out, nTask);
}

// Round 5
// 139.957 us; speedup vs baseline: 1.0375x; 1.0104x over previous
//
#include <hip/hip_runtime.h>
#include <hip/hip_bf16.h>

#define DIMSZ 256
#define HID 4096
#define BATCH 4
#define SEQ 2048
#define NCH 64      // chunks per sequence (carry granularity)
#define CLEN 32     // chunk length
#define SPLITK2 4   // K-splits for fused GEMM2
#define KCHUNK (HID / SPLITK2)   // 1024 channels per block
#define BM2 32      // timesteps per fused-GEMM2 block (= 1 chunk)

typedef __bf16 bf16_t;
typedef __bf16 bf16x4 __attribute__((ext_vector_type(4)));
typedef __bf16 bf16x8 __attribute__((ext_vector_type(8)));
typedef float  f32x4  __attribute__((ext_vector_type(4)));

__device__ __forceinline__ float sigmoidf_dev(float x) {
    return 1.0f / (1.0f + __expf(-x));
}

__device__ __forceinline__ bf16x8 cvt8(const float* p) {
    bf16x8 o;
    #pragma unroll
    for (int j = 0; j < 8; j++) o[j] = (bf16_t)p[j];
    return o;
}

// ---------------- prep: fused fp32->bf16 convert + MFMA-frag swizzle ----------------
__global__ void prep_kernel(const float* __restrict__ x,
                            const float* __restrict__ WB,
                            const float* __restrict__ WC,
                            bf16_t* __restrict__ xt,
                            bf16_t* __restrict__ WBt,
                            bf16_t* __restrict__ Wt) {
    int i = blockIdx.x * blockDim.x + threadIdx.x;   // 524288
    if (i < 262144) {                                // xt
        int lane = i & 63, m16 = (i >> 6) & 511, ks = i >> 15;
        int row = m16 * 16 + (lane & 15);
        int k   = ks * 32 + (lane >> 4) * 8;
        *(bf16x8*)&xt[(size_t)i * 8] = cvt8(&x[(size_t)row * DIMSZ + k]);
    } else if (i < 393216) {                         // WBt
        int j = i - 262144;
        int lane = j & 63, n16 = (j >> 6) & 255, ks = j >> 14;
        int row = n16 * 16 + (lane & 15);
        int k   = ks * 32 + (lane >> 4) * 8;
        *(bf16x8*)&WBt[(size_t)j * 8] = cvt8(&WB[(size_t)row * DIMSZ + k]);
    } else {                                         // Wt
        int j = i - 393216;
        int lane = j & 63, g = (j >> 6) & 15, ks = j >> 10;
        int row = g * 16 + (lane & 15);
        int k   = ks * 32 + (lane >> 4) * 8;
        *(bf16x8*)&Wt[(size_t)j * 8] = cvt8(&WC[(size_t)row * HID + k]);
    }
}

// ---------------- GEMM1 fused: b = x@WB^T + bB (bf16, chunk-blocked out), + totals ----
// tile is [ch][t] (LDT=136). Writeback targets bbuf[batch][chunk][ch][32t]:
// per (ch,chunk) a 64-B contiguous row; consecutive ch rows adjacent -> coalesced.
__global__ __launch_bounds__(256)
void gemm1_fused(const bf16_t* __restrict__ xt, const bf16_t* __restrict__ WBt,
                 const float* __restrict__ bias, const float* __restrict__ Adecay,
                 bf16_t* __restrict__ Cg, float* __restrict__ totals)
{
    constexpr int LDT = 136;                // elems; 272 B row stride (16B-aligned)
    __shared__ bf16_t tile[128 * LDT];      // 34.8 KB, [ch][t]

    const int tid = threadIdx.x, wave = tid >> 6, lane = tid & 63;
    const int wm = wave >> 1, wn = wave & 1, q = lane >> 4, r16 = lane & 15;
    const int mBase = blockIdx.x * 128, nBase = blockIdx.y * 128;
    const int m16Base = blockIdx.x * 8 + wm * 4;
    const int n16Base = blockIdx.y * 8 + wn * 4;
    const int batch = mBase >> 11, tIn = mBase & 2047;
    const int cg0 = tIn >> 5;               // first of 4 chunks this block covers

    f32x4 acc[4][4] = {};

    #pragma unroll 2
    for (int ks = 0; ks < 8; ks++) {
        bf16x8 af[4], bfr[4];
        #pragma unroll
        for (int mt = 0; mt < 4; mt++)
            af[mt] = *(const bf16x8*)&xt[(((size_t)ks * 512 + m16Base + mt) * 64 + lane) * 8];
        #pragma unroll
        for (int nt = 0; nt < 4; nt++)
            bfr[nt] = *(const bf16x8*)&WBt[(((size_t)ks * 256 + n16Base + nt) * 64 + lane) * 8];
        #pragma unroll
        for (int mt = 0; mt < 4; mt++)
            #pragma unroll
            for (int nt = 0; nt < 4; nt++)
                acc[mt][nt] = __builtin_amdgcn_mfma_f32_16x16x32_bf16(
                    af[mt], bfr[nt], acc[mt][nt], 0, 0, 0);
    }

    // acc (+bias) -> [ch][t] tile, packed b64 (4 consecutive t per acc quad)
    #pragma unroll
    for (int nt = 0; nt < 4; nt++) {
        const int chl = wn * 64 + nt * 16 + r16;
        const float bv = bias[nBase + chl];
        #pragma unroll
        for (int mt = 0; mt < 4; mt++) {
            const int t0 = wm * 64 + mt * 16 + q * 4;
            bf16x4 pk;
            #pragma unroll
            for (int rg = 0; rg < 4; rg++)
                pk[rg] = (bf16_t)(acc[mt][nt][rg] + bv);
            *(bf16x4*)&tile[chl * LDT + t0] = pk;
        }
    }
    __syncthreads();

    // writeback: chunk-blocked bbuf [batch*NCH+chunk][ch][32]
    #pragma unroll
    for (int p = 0; p < 8; p++) {
        const int task = p * 256 + tid;
        const int ch = task >> 4, o = task & 15;
        const int cc = o >> 2, oo = o & 3;
        *(bf16x8*)&Cg[((size_t)(batch * NCH + cg0 + cc) * HID + nBase + ch) * 32 + oo * 8] =
            *(const bf16x8*)&tile[ch * LDT + o * 8];
    }

    // chunk totals: vectorized b128 reads along t
    #pragma unroll
    for (int t = 0; t < 2; t++) {
        const int task = tid + t * 256;
        const int ch = task & 127, ck = task >> 7;
        const float a = sigmoidf_dev(Adecay[nBase + ch]);
        float tot = 0.f;
        #pragma unroll
        for (int o = 0; o < 4; o++) {
            bf16x8 v8 = *(const bf16x8*)&tile[ch * LDT + ck * CLEN + o * 8];
            #pragma unroll
            for (int j = 0; j < 8; j++)
                tot = a * tot + (float)v8[j];
        }
        totals[(size_t)(batch * NCH + cg0 + ck) * HID + nBase + ch] = tot;
    }
}

// ---------------- scan over chunk carries, register-batched ----------------
__global__ void scan_carries_kernel(const float* __restrict__ totals,
                                    const float* __restrict__ Adecay,
                                    float* __restrict__ carries)
{
    int gid = blockIdx.x * 64 + threadIdx.x;   // BATCH*HID
    int ch    = gid & (HID - 1);
    int batch = gid >> 12;
    float a = sigmoidf_dev(Adecay[ch]);
    float aC = a;
    #pragma unroll
    for (int i = 0; i < 5; i++) aC *= aC;      // a^32

    float v[NCH];
    #pragma unroll
    for (int c = 0; c < NCH; c++)
        v[c] = totals[(size_t)(batch * NCH + c) * HID + ch];

    float carry = 0.f;
    #pragma unroll
    for (int c = 0; c < NCH; c++) {
        carries[(size_t)(batch * NCH + c) * HID + ch] = carry;
        carry = aC * carry + v[c];
    }
}

// ---------------- fused scan + GEMM2 split-K (register-staged, 4 blocks/CU) --------
// Per block: 32 timesteps (1 chunk) x N=256 x 1024-ch K-slice, 4 slabs of 256 ch.
// No LDS staging: each thread loads its channel's 32 t (4x b128, contiguous in the
// chunk-blocked bbuf) straight to registers, ping-ponged so slab s+1's loads hide
// under scan+MFMA of slab s. hs is a double-buffered MFMA tile -> ONE barrier per
// slab. 33.8 KB LDS + <=128 VGPR -> 4 blocks/CU (grid 1024 = 4/CU exactly).
#define SCAN_SLAB(REG, S)                                                   \
    do {                                                                    \
        const float a = sigmoidf_dev(aD[S]);                                \
        float st = sd[S];                                                   \
        bf16_t* hw = &hs[(S) & 1][(tid >> 5) * CKSTRIDE + (tid & 31)];      \
        _Pragma("unroll")                                                   \
        for (int o = 0; o < 4; o++) {                                       \
            _Pragma("unroll")                                               \
            for (int j = 0; j < 8; j++) {                                   \
                st = a * st + (float)REG[o][j];                             \
                hw[(o * 8 + j) * 32] = (bf16_t)st;                          \
            }                                                               \
        }                                                                   \
    } while (0)

__global__ __launch_bounds__(256, 4)
void gemm2_fused(const bf16_t* __restrict__ bv, const bf16_t* __restrict__ Wt,
                 const float* __restrict__ Adecay, const float* __restrict__ carries,
                 bf16_t* __restrict__ P)
{
    constexpr int CKSTRIDE = CLEN * 32 + 32;   // 1056: +64B stagger between ck slabs
    __shared__ bf16_t hs[2][8 * CKSTRIDE];     // 2 x 16.9 KB; [0] doubles as epilogue tile

    const int tid = threadIdx.x, wave = tid >> 6, lane = tid & 63;
    const int q = lane >> 4, r16 = lane & 15;
    const int mBase = blockIdx.x * BM2;
    const int kBase = blockIdx.y * KCHUNK;
    const int batch = mBase >> 11, tIn = mBase & 2047;
    const int chunk = tIn >> 5;

    // this thread's channel row in chunk-blocked bbuf (slab s: +s*256*32 elems)
    const size_t rowBase = ((size_t)(batch * NCH + chunk) * HID + kBase + tid) * 32;

    // issue slab-0 loads first (longest latency)
    bf16x8 rA[4], rB[4];
    #pragma unroll
    for (int o = 0; o < 4; o++)
        rA[o] = *(const bf16x8*)&bv[rowBase + o * 8];

    // per-slab scan constants
    float aD[4], sd[4];
    #pragma unroll
    for (int s = 0; s < 4; s++) {
        const int c = kBase + s * 256 + tid;
        aD[s] = Adecay[c];
        sd[s] = carries[(size_t)(batch * NCH + chunk) * HID + c];
    }

    f32x4 acc[2][4] = {};

    auto mfma_phase = [&](const bf16_t* hb, int s) {
        const int ksBase = (kBase >> 5) + s * 8;
        #pragma unroll 2
        for (int cki = 0; cki < 8; cki++) {
            bf16x8 af[2], bfr[4];
            #pragma unroll
            for (int nt = 0; nt < 4; nt++)
                bfr[nt] = *(const bf16x8*)&Wt[
                    (((size_t)(ksBase + cki) * 16 + wave * 4 + nt) * 64 + lane) * 8];
            #pragma unroll
            for (int mt = 0; mt < 2; mt++)
                af[mt] = *(const bf16x8*)&hb[cki * CKSTRIDE + (mt * 16 + r16) * 32 + q * 8];
            #pragma unroll
            for (int mt = 0; mt < 2; mt++)
                #pragma unroll
                for (int nt = 0; nt < 4; nt++)
                    acc[mt][nt] = __builtin_amdgcn_mfma_f32_16x16x32_bf16(
                        af[mt], bfr[nt], acc[mt][nt], 0, 0, 0);
        }
    };

    // ---- slab 0 ----
    #pragma unroll
    for (int o = 0; o < 4; o++)
        rB[o] = *(const bf16x8*)&bv[rowBase + 1 * 8192 + o * 8];
    SCAN_SLAB(rA, 0);
    __syncthreads();
    mfma_phase(&hs[0][0], 0);

    // ---- slab 1 ----
    #pragma unroll
    for (int o = 0; o < 4; o++)
        rA[o] = *(const bf16x8*)&bv[rowBase + 2 * 8192 + o * 8];
    SCAN_SLAB(rB, 1);
    __syncthreads();
    mfma_phase(&hs[1][0], 1);

    // ---- slab 2 ----
    #pragma unroll
    for (int o = 0; o < 4; o++)
        rB[o] = *(const bf16x8*)&bv[rowBase + 3 * 8192 + o * 8];
    SCAN_SLAB(rA, 2);
    __syncthreads();
    mfma_phase(&hs[0][0], 2);

    // ---- slab 3 ----
    SCAN_SLAB(rB, 3);
    __syncthreads();
    mfma_phase(&hs[1][0], 3);

    // epilogue: acc -> bf16 tile in hs[0] (all hs[0] readers finished by the
    // slab-3 barrier; concurrent MFMA s=3 readers touch only hs[1])
    #pragma unroll
    for (int nt = 0; nt < 4; nt++) {
        const int col = wave * 64 + nt * 16 + r16;
        #pragma unroll
        for (int mt = 0; mt < 2; mt++)
            #pragma unroll
            for (int rg = 0; rg < 4; rg++)
                hs[0][(mt * 16 + q * 4 + rg) * 264 + col] = (bf16_t)acc[mt][nt][rg];
    }
    __syncthreads();

    bf16_t* Pb = P + (size_t)blockIdx.y * (BATCH * SEQ) * DIMSZ;
    #pragma unroll
    for (int p = 0; p < 4; p++) {
        int task = p * 256 + tid;
        int r = task >> 5, g8 = (task & 31) << 3;
        *(bf16x8*)&Pb[(size_t)(mBase + r) * DIMSZ + g8] =
            *(const bf16x8*)&hs[0][r * 264 + g8];
    }
}

// ---------------- reduce bf16 partials + bias -> fp32 d_out ----------------
__global__ void reduce_out_kernel(const bf16_t* __restrict__ P,
                                  const float* __restrict__ bias,
                                  float* __restrict__ out, int nTask) {
    int i = blockIdx.x * blockDim.x + threadIdx.x;   // M*256/8
    if (i >= nTask) return;
    int n8 = (i & 31) << 3;
    size_t off = (size_t)i * 8;
    float v[8];
    #pragma unroll
    for (int j = 0; j < 8; j++) v[j] = bias[n8 + j];
    #pragma unroll
    for (int sp = 0; sp < SPLITK2; sp++) {
        bf16x8 p = *(const bf16x8*)&P[(size_t)sp * (BATCH * SEQ) * DIMSZ + off];
        #pragma unroll
        for (int j = 0; j < 8; j++) v[j] += (float)p[j];
    }
    float4* o4 = (float4*)&out[off];
    o4[0] = make_float4(v[0], v[1], v[2], v[3]);
    o4[1] = make_float4(v[4], v[5], v[6], v[7]);
}

extern "C" void kernel_launch(void* const* d_in, const int* in_sizes, int n_in,
                              void* d_out, int out_size, void* d_ws, size_t ws_size,
                              hipStream_t stream)
{
    const float* x  = (const float*)d_in[0];
    const float* WB = (const float*)d_in[1];
    const float* bB = (const float*)d_in[2];
    const float* WC = (const float*)d_in[3];
    const float* bC = (const float*)d_in[4];
    const float* A  = (const float*)d_in[5];

    char* ws = (char*)d_ws;
    size_t off = 0;
    bf16_t* xt   = (bf16_t*)(ws + off); off += (size_t)BATCH * SEQ * DIMSZ * 2;  // 4 MB
    bf16_t* WBt  = (bf16_t*)(ws + off); off += (size_t)HID * DIMSZ * 2;          // 2 MB
    bf16_t* Wt   = (bf16_t*)(ws + off); off += (size_t)DIMSZ * HID * 2;          // 2 MB
    bf16_t* bbuf = (bf16_t*)(ws + off); off += (size_t)BATCH * SEQ * HID * 2;    // 64 MB, chunk-blocked
    bf16_t* partials = (bf16_t*)(ws + off); off += (size_t)SPLITK2 * BATCH * SEQ * DIMSZ * 2; // 16.75 MB
    float* totals   = (float*)(ws + off); off += (size_t)BATCH * NCH * HID * 4;
    float* carries  = (float*)(ws + off); off += (size_t)BATCH * NCH * HID * 4;

    const int M = BATCH * SEQ;   // 8192

    prep_kernel<<<2048, 256, 0, stream>>>(x, WB, WC, xt, WBt, Wt);

    dim3 g1(M / 128, HID / 128);
    gemm1_fused<<<g1, 256, 0, stream>>>(xt, WBt, bB, A, bbuf, totals);

    scan_carries_kernel<<<256, 64, 0, stream>>>(totals, A, carries);

    dim3 g2(M / BM2, SPLITK2);
    gemm2_fused<<<g2, 256, 0, stream>>>(bbuf, Wt, A, carries, partials);

    int nTask = M * DIMSZ / 8;
    reduce_out_kernel<<<(nTask + 255) / 256, 256, 0, stream>>>(
        partials, bC, (float*)d_out, nTask);
}